// Round 7
// baseline (237.641 us; speedup 1.0000x reference)
//
#include <hip/hip_runtime.h>

#define N_NODES 10000
#define N_EDGES 100000
#define SLOTS 40   // max degree bound; Poisson(10), P(deg>=40) ~ 1e-12

typedef __attribute__((ext_vector_type(8))) _Float16 f16x8;
typedef __attribute__((ext_vector_type(2))) _Float16 f16x2;
typedef __attribute__((ext_vector_type(4))) float f32x4;

// __builtin_amdgcn_cvt_pkrtz returns __fp16x2; rewrap bits as _Float16x2.
static __device__ inline f16x2 pkrtz(float a, float b) {
    auto t = __builtin_amdgcn_cvt_pkrtz(a, b);
    union { decltype(t) x; f16x2 y; } u;
    u.x = t;
    return u.y;
}
static __device__ inline unsigned short f16u(float x) {
    union { _Float16 h; unsigned short s; } u;
    u.h = (_Float16)x;
    return u.s;
}
static __device__ inline float f16f(unsigned short us) {
    union { unsigned short s; _Float16 h; } u;
    u.s = us;
    return (float)u.h;
}
static __device__ inline f16x8 cvt8h(const float* f) {
    f16x8 r; f16x2* rp = (f16x2*)&r;
#pragma unroll
    for (int i = 0; i < 4; ++i) rp[i] = pkrtz(f[2 * i], f[2 * i + 1]);
    return r;
}
static __device__ inline f16x8 scale8(f16x2 h2, f16x8 x) {
    f16x8 r; f16x2* rp = (f16x2*)&r; f16x2* xp = (f16x2*)&x;
#pragma unroll
    for (int i = 0; i < 4; ++i) rp[i] = h2 * xp[i];
    return r;
}
static __device__ inline int pack2(float a, float b) {
    union { f16x2 h; int i; } u;
    u.h = pkrtz(a, b);
    return u.i;
}

// ---------------------------------------------------------------------------
// Prep kernel (fold-only): 64 blocks x 1024 threads. Tables emitted as F16.
// cnt[0..N_NODES] zeroed (cnt[N_NODES] = fused kernel's barrier counter).
// ---------------------------------------------------------------------------
__global__ __launch_bounds__(1024) void prep_kernel(
    const float* __restrict__ Wgen, const float* __restrict__ L1s,
    const float* __restrict__ L1v, const float* __restrict__ WS0,
    const float* __restrict__ WS1, const float* __restrict__ L2s,
    const float* __restrict__ L2v, unsigned short* __restrict__ Wc,
    unsigned short* __restrict__ WB0, unsigned short* __restrict__ WB1,
    int* __restrict__ cnt) {
    const float S = 1.0f / 128.0f;
    int tid = blockIdx.x * 1024 + threadIdx.x;   // 0..65535
    if (tid <= N_NODES) cnt[tid] = 0;            // slot counters + barrier
    if (tid < 32768) {
        int j = tid & 7;
        int lane = (tid >> 3) & 63;
        int ks = (tid >> 9) & 7;
        int nt = tid >> 12;
        int col = nt * 16 + (lane & 15);
        int u = (lane >> 4) * 8 + j;
        int r = ks;
        int p, c2;
        const float* M;
        float sc = S;
        if (col < 32)      { p = 0; M = L1s; c2 = col; }
        else if (col < 64) { p = 1; M = L1v; c2 = col - 32; }
        else if (col < 96) { p = 2; M = L1v; c2 = col - 64; }
        else               { p = 3; M = L1s; c2 = col - 96; sc = S * 0.57735026918962576f; }
        const float* wg = Wgen + r * 4096 + p * 1024 + u * 32;
        float acc = 0.f;
#pragma unroll
        for (int w = 0; w < 32; ++w) acc += wg[w] * M[w * 32 + c2];
        Wc[tid] = f16u(acc * sc);
    } else {
        int idx = tid - 32768;
        int table = idx >> 14;
        int r14 = idx & 16383;
        int j = r14 & 7;
        int lane = (r14 >> 3) & 63;
        int ks = (r14 >> 9) & 15;
        int k = ks * 32 + (lane >> 4) * 8 + j;
        int u = k >> 4, v = k & 15;
        int w = ((r14 >> 13) & 1) * 16 + (lane & 15);
        const float* WS = table ? WS1 : WS0;
        const float* L2 = table ? L2v : L2s;
        const float* src = WS + u * 512 + v * 32;
        float acc = 0.f;
#pragma unroll
        for (int x = 0; x < 32; ++x) acc += src[x] * L2[x * 32 + w];
        unsigned short val = f16u(acc * S);
        if (table) WB1[r14] = val; else WB0[r14] = val;
    }
}

// ---------------------------------------------------------------------------
// FUSED kernel v12: edge phase + all-resident grid barrier + node phase.
//  - 512 blocks x 256 thr; LDS 66KB -> 2 blocks/CU, launch_bounds(256,2)
//    caps VGPR at 256 -> 8 waves/CU -> all 512 blocks co-resident (barrier
//    is safe by construction). bar = cnt[N_NODES], zeroed by prep each run.
//  - Phase 1: R6's f16 edge loop (2-deep idx prefetch, packed A-builds).
//  - Barrier: syncthreads + threadfence (agent release: flushes per-XCD L2,
//    Guideline 16) + atomic count + spin + acquire fence.
//  - Phase 2: node work grid-strided over 625 blocks-of-16-nodes; Msg read
//    warm from MALL; gather = 16 unconditional loads + predicated adds (one
//    latency round for 97% of nodes). cnt read via device-scope atomic load.
// ---------------------------------------------------------------------------
__global__ __launch_bounds__(256, 2) void fused_kernel(
    const float* __restrict__ node_feats, const float* __restrict__ edge_attrs,
    const float* __restrict__ edge_feats, const int* __restrict__ edge_index,
    const unsigned short* __restrict__ Wc, int* __restrict__ cnt,
    unsigned short* __restrict__ Msg, const float* __restrict__ node_attrs,
    const unsigned short* __restrict__ WB0, const unsigned short* __restrict__ WB1,
    float* __restrict__ out) {
    __shared__ union {
        struct { f16x8 w[4096]; int sl[4][16]; f32x4 ea[4][16]; } p1;  // 66.8KB
        struct { float sM[16][129]; float sAt[16][17]; } p2;           //  9.3KB
    } su;

    {
        const f16x8* src = (const f16x8*)Wc;
        for (int i = threadIdx.x; i < 4096; i += 256) su.p1.w[i] = src[i];
    }
    __syncthreads();

    const int lane = threadIdx.x & 63;
    const int m = lane & 15, q = lane >> 4;
    const int wv = threadIdx.x >> 6;
    const int wave = (blockIdx.x * 256 + threadIdx.x) >> 6;
    const int stride = gridDim.x * 4;
    const int NT = N_EDGES / 16;

    int tile = wave;   // wave < 2048 < NT always -> every wave runs >=1 tile

    f16x8 xs8, xv8[3], dt8;
    float efC[8];
    f32x4 eaC;
    int slC = 0;

    // ---- prologue: gather + convert for first tile; idx prefetch for +stride
    {
        int e = tile * 16 + m;
        int snd = edge_index[e];
        if (lane < 16) {
            int r = edge_index[N_EDGES + e];
            slC = r * SLOTS + atomicAdd(&cnt[r], 1);
        }
        const float* g = node_feats + snd * 128;
        float xs[8], xv[24];
        *(f32x4*)&xs[0] = *(const f32x4*)(g + q * 8);
        *(f32x4*)&xs[4] = *(const f32x4*)(g + q * 8 + 4);
#pragma unroll
        for (int i = 0; i < 6; ++i)
            *(f32x4*)&xv[i * 4] = *(const f32x4*)(g + 32 + q * 24 + i * 4);
        *(f32x4*)&efC[0] = *(const f32x4*)(edge_feats + e * 8);
        *(f32x4*)&efC[4] = *(const f32x4*)(edge_feats + e * 8 + 4);
        eaC = *(const f32x4*)(edge_attrs + e * 4);
        float dt[8];
        float y0 = eaC.y, y1 = eaC.z, y2 = eaC.w;
#pragma unroll
        for (int j = 0; j < 8; ++j)
            dt[j] = xv[j * 3] * y0 + xv[j * 3 + 1] * y1 + xv[j * 3 + 2] * y2;
        xs8 = cvt8h(xs);
#pragma unroll
        for (int c = 0; c < 3; ++c) {
            f16x8 r; f16x2* rp = (f16x2*)&r;
#pragma unroll
            for (int i = 0; i < 4; ++i)
                rp[i] = pkrtz(xv[(2 * i) * 3 + c], xv[(2 * i + 1) * 3 + c]);
            xv8[c] = r;
        }
        dt8 = cvt8h(dt);
    }
    int snd1 = 0, rcv1 = 0;
    {
        int t1 = tile + stride;
        if (t1 < NT) {
            int e1 = t1 * 16 + m;
            snd1 = edge_index[e1];
            if (lane < 16) rcv1 = edge_index[N_EDGES + e1];
        }
    }

    while (tile < NT) {
        const int tn = tile + stride;
        const bool hasN = tn < NT;
        const int t2 = tile + 2 * stride;
        const bool has2 = t2 < NT;

        if (lane < 16) {
            su.p1.sl[wv][lane] = slC;
            su.p1.ea[wv][lane] = eaC;
        }

        // ---- prefetch tile+s raw state (in-register indices, no dep wait)
        float xsN[8], xvN[24], efN[8];
        f32x4 eaN;
        int slN = 0;
        if (hasN) {
            int en = tn * 16 + m;
            if (lane < 16) slN = rcv1 * SLOTS + atomicAdd(&cnt[rcv1], 1);
            const float* gN = node_feats + snd1 * 128;
            *(f32x4*)&xsN[0] = *(const f32x4*)(gN + q * 8);
            *(f32x4*)&xsN[4] = *(const f32x4*)(gN + q * 8 + 4);
#pragma unroll
            for (int i = 0; i < 6; ++i)
                *(f32x4*)&xvN[i * 4] = *(const f32x4*)(gN + 32 + q * 24 + i * 4);
            *(f32x4*)&efN[0] = *(const f32x4*)(edge_feats + en * 8);
            *(f32x4*)&efN[4] = *(const f32x4*)(edge_feats + en * 8 + 4);
            eaN = *(const f32x4*)(edge_attrs + en * 4);
        }

        // ---- prefetch tile+2s indices
        int snd2 = 0, rcv2 = 0;
        if (has2) {
            int e2 = t2 * 16 + m;
            snd2 = edge_index[e2];
            if (lane < 16) rcv2 = edge_index[N_EDGES + e2];
        }

        // ---- compute current tile (f16 packed A-builds)
        f32x4 z = {0.f, 0.f, 0.f, 0.f};
        f32x4 fA[2] = {z, z}, fB[2] = {z, z}, fD[2] = {z, z};
        f32x4 fC[3][2] = {{z, z}, {z, z}, {z, z}};

#pragma unroll
        for (int ks = 0; ks < 8; ++ks) {
            _Float16 h = (_Float16)efC[ks];
            f16x2 h2 = {h, h};
            {
                f16x8 a = scale8(h2, xs8);
                fA[0] = __builtin_amdgcn_mfma_f32_16x16x32_f16(a, su.p1.w[(0 * 8 + ks) * 64 + lane], fA[0], 0, 0, 0);
                fA[1] = __builtin_amdgcn_mfma_f32_16x16x32_f16(a, su.p1.w[(1 * 8 + ks) * 64 + lane], fA[1], 0, 0, 0);
                fB[0] = __builtin_amdgcn_mfma_f32_16x16x32_f16(a, su.p1.w[(2 * 8 + ks) * 64 + lane], fB[0], 0, 0, 0);
                fB[1] = __builtin_amdgcn_mfma_f32_16x16x32_f16(a, su.p1.w[(3 * 8 + ks) * 64 + lane], fB[1], 0, 0, 0);
            }
            {
                f16x8 bc0 = su.p1.w[(4 * 8 + ks) * 64 + lane];
                f16x8 bc1 = su.p1.w[(5 * 8 + ks) * 64 + lane];
#pragma unroll
                for (int c = 0; c < 3; ++c) {
                    f16x8 a = scale8(h2, xv8[c]);
                    fC[c][0] = __builtin_amdgcn_mfma_f32_16x16x32_f16(a, bc0, fC[c][0], 0, 0, 0);
                    fC[c][1] = __builtin_amdgcn_mfma_f32_16x16x32_f16(a, bc1, fC[c][1], 0, 0, 0);
                }
            }
            {
                f16x8 a = scale8(h2, dt8);
                fD[0] = __builtin_amdgcn_mfma_f32_16x16x32_f16(a, su.p1.w[(6 * 8 + ks) * 64 + lane], fD[0], 0, 0, 0);
                fD[1] = __builtin_amdgcn_mfma_f32_16x16x32_f16(a, su.p1.w[(7 * 8 + ks) * 64 + lane], fD[1], 0, 0, 0);
            }
        }

        // ---- epilogue
        int4 sl4 = *(const int4*)&su.p1.sl[wv][q * 4];
        const int slR[4] = {sl4.x, sl4.y, sl4.z, sl4.w};
#pragma unroll
        for (int t4 = 0; t4 < 4; ++t4) {
            f32x4 ea4 = su.p1.ea[wv][q * 4 + t4];
            float ysr = ea4.x, y0r = ea4.y, y1r = ea4.z, y2r = ea4.w;
            int dr = slR[t4];
#pragma unroll
            for (int nt = 0; nt < 2; ++nt) {
                int col = nt * 16 + m;
                float pb = fB[nt][t4];
                int2 pk;
                pk.x = pack2(ysr * fA[nt][t4] + fD[nt][t4],
                             y0r * pb + ysr * fC[0][nt][t4]);
                pk.y = pack2(y1r * pb + ysr * fC[1][nt][t4],
                             y2r * pb + ysr * fC[2][nt][t4]);
                *(int2*)(Msg + (size_t)dr * 128 + col * 4) = pk;
            }
        }

        // ---- rotate pipeline
        tile = tn;
        if (hasN) {
            float dtN[8];
            float y0 = eaN.y, y1 = eaN.z, y2 = eaN.w;
#pragma unroll
            for (int j = 0; j < 8; ++j)
                dtN[j] = xvN[j * 3] * y0 + xvN[j * 3 + 1] * y1 + xvN[j * 3 + 2] * y2;
            xs8 = cvt8h(xsN);
#pragma unroll
            for (int c = 0; c < 3; ++c) {
                f16x8 r; f16x2* rp = (f16x2*)&r;
#pragma unroll
                for (int i = 0; i < 4; ++i)
                    rp[i] = pkrtz(xvN[(2 * i) * 3 + c], xvN[(2 * i + 1) * 3 + c]);
                xv8[c] = r;
            }
            dt8 = cvt8h(dtN);
#pragma unroll
            for (int j = 0; j < 8; ++j) efC[j] = efN[j];
            eaC = eaN;
            slC = slN;
            snd1 = snd2;
            rcv1 = rcv2;
        }
    }

    // =========================== GRID BARRIER ===============================
    __syncthreads();           // all waves of this block done with phase 1
    __threadfence();           // agent-scope release: flush Msg/cnt writes
    int* bar = cnt + N_NODES;
    if (threadIdx.x == 0) {
        __hip_atomic_fetch_add(bar, 1, __ATOMIC_ACQ_REL, __HIP_MEMORY_SCOPE_AGENT);
        while (__hip_atomic_load(bar, __ATOMIC_ACQUIRE, __HIP_MEMORY_SCOPE_AGENT)
               < (int)gridDim.x) {
            __builtin_amdgcn_s_sleep(8);
        }
    }
    __syncthreads();
    __threadfence();           // acquire side

    // =========================== NODE PHASE =================================
    const int tid = threadIdx.x;
    for (int nb = blockIdx.x; nb < 625; nb += gridDim.x) {
        __syncthreads();       // protect sM reuse across grid-stride rounds
        int n0 = nb * 16;
        int nl = tid >> 4;
        int cg = tid & 15;
        int n = n0 + nl;
        int deg = __hip_atomic_load(&cnt[n], __ATOMIC_RELAXED, __HIP_MEMORY_SCOPE_AGENT);
        int s0 = n * SLOTS;
        float acc[8];
#pragma unroll
        for (int j = 0; j < 8; ++j) acc[j] = 0.f;
        // 16 unconditional loads (slots always in-bounds), predicated adds
        {
            f32x4 r[16];
#pragma unroll
            for (int i = 0; i < 16; ++i)
                r[i] = *(const f32x4*)(Msg + (size_t)(s0 + i) * 128 + cg * 8);
#pragma unroll
            for (int i = 0; i < 16; ++i) {
                if (i < deg) {
                    const unsigned short* us = (const unsigned short*)&r[i];
#pragma unroll
                    for (int j = 0; j < 8; ++j) acc[j] += f16f(us[j]);
                }
            }
        }
        for (int s = s0 + 16; s < s0 + deg; ++s) {   // rare deg>16 tail
            f32x4 raw = *(const f32x4*)(Msg + (size_t)s * 128 + cg * 8);
            const unsigned short* us = (const unsigned short*)&raw;
#pragma unroll
            for (int j = 0; j < 8; ++j) acc[j] += f16f(us[j]);
        }
#pragma unroll
        for (int j = 0; j < 8; ++j)
            su.p2.sM[nl][(j & 3) * 32 + cg * 2 + (j >> 2)] = acc[j];
        su.p2.sAt[nl][cg] = node_attrs[n * 16 + cg];
        __syncthreads();

        int p = tid >> 6;
        int ml = lane & 15, ql = lane >> 4;
        const unsigned short* WB = (p == 0) ? WB0 : WB1;
        int chb = p * 32;
        f32x4 z2 = {0.f, 0.f, 0.f, 0.f};
        f32x4 D0 = z2, D1 = z2;
#pragma unroll
        for (int ks = 0; ks < 16; ++ks) {
            int kb = ks * 32 + ql * 8;
            float t[8];
#pragma unroll
            for (int j = 0; j < 8; ++j) {
                int k = kb + j;
                t[j] = su.p2.sM[ml][chb + (k >> 4)] * su.p2.sAt[ml][k & 15];
            }
            f16x8 a = cvt8h(t);
            f16x8 b0 = *(const f16x8*)(WB + (ks * 64 + lane) * 8);
            f16x8 b1 = *(const f16x8*)(WB + ((16 + ks) * 64 + lane) * 8);
            D0 = __builtin_amdgcn_mfma_f32_16x16x32_f16(a, b0, D0, 0, 0, 0);
            D1 = __builtin_amdgcn_mfma_f32_16x16x32_f16(a, b1, D1, 0, 0, 0);
        }

#pragma unroll
        for (int t4 = 0; t4 < 4; ++t4) {
            int nl2 = ql * 4 + t4;
            int nn = n0 + nl2;
            if (p == 0) {
                out[nn * 128 + ml]      = su.p2.sM[nl2][ml] + D0[t4];
                out[nn * 128 + 16 + ml] = su.p2.sM[nl2][16 + ml] + D1[t4];
            } else {
                int i = p - 1;
                out[nn * 128 + 32 + ml * 3 + i]        = su.p2.sM[nl2][chb + ml] + D0[t4];
                out[nn * 128 + 32 + (16 + ml) * 3 + i] = su.p2.sM[nl2][chb + 16 + ml] + D1[t4];
            }
        }
    }
}

extern "C" void kernel_launch(void* const* d_in, const int* in_sizes, int n_in,
                              void* d_out, int out_size, void* d_ws, size_t ws_size,
                              hipStream_t stream) {
    (void)in_sizes; (void)n_in; (void)out_size; (void)ws_size;
    const float* node_attrs = (const float*)d_in[0];
    const float* node_feats = (const float*)d_in[1];
    const float* edge_attrs = (const float*)d_in[2];
    const float* edge_feats = (const float*)d_in[3];
    const int*   edge_index = (const int*)d_in[4];
    const float* Wgen = (const float*)d_in[5];
    const float* L1s  = (const float*)d_in[6];
    const float* L1v  = (const float*)d_in[7];
    const float* WS0  = (const float*)d_in[8];
    const float* WS1  = (const float*)d_in[9];
    const float* L2s  = (const float*)d_in[10];
    const float* L2v  = (const float*)d_in[11];
    float* out = (float*)d_out;
    char* ws = (char*)d_ws;

    // Msg: N_NODES*SLOTS rows x 128 f16 = 102,400,000 B (ws is 256 MiB)
    unsigned short* Msg = (unsigned short*)ws;
    unsigned short* Wc  = (unsigned short*)(ws + 102400000);   // 65,536
    unsigned short* WB0 = (unsigned short*)(ws + 102465536);   // 32,768
    unsigned short* WB1 = (unsigned short*)(ws + 102498304);   // 32,768
    int* cnt = (int*)(ws + 102531072);                         // 10001 ints
                                                               // (cnt[N_NODES] = barrier)

    prep_kernel<<<64, 1024, 0, stream>>>(Wgen, L1s, L1v, WS0, WS1, L2s, L2v,
                                         Wc, WB0, WB1, cnt);
    fused_kernel<<<512, 256, 0, stream>>>(node_feats, edge_attrs, edge_feats,
                                          edge_index, Wc, cnt, Msg, node_attrs,
                                          WB0, WB1, out);
}

// Round 9
// 129.806 us; speedup vs baseline: 1.8307x; 1.8307x over previous
//
#include <hip/hip_runtime.h>

#define N_NODES 10000
#define N_EDGES 100000
#define SLOTS 40   // max degree bound; Poisson(10), P(deg>=40) ~ 1e-12

typedef __attribute__((ext_vector_type(8))) _Float16 f16x8;
typedef __attribute__((ext_vector_type(2))) _Float16 f16x2;
typedef __attribute__((ext_vector_type(4))) float f32x4;

// __builtin_amdgcn_cvt_pkrtz returns __fp16x2; rewrap bits as _Float16x2.
static __device__ inline f16x2 pkrtz(float a, float b) {
    auto t = __builtin_amdgcn_cvt_pkrtz(a, b);
    union { decltype(t) x; f16x2 y; } u;
    u.x = t;
    return u.y;
}
static __device__ inline unsigned short f16u(float x) {
    union { _Float16 h; unsigned short s; } u;
    u.h = (_Float16)x;
    return u.s;
}
static __device__ inline float f16f(unsigned short us) {
    union { unsigned short s; _Float16 h; } u;
    u.s = us;
    return (float)u.h;
}
static __device__ inline f16x8 cvt8h(const float* f) {
    f16x8 r; f16x2* rp = (f16x2*)&r;
#pragma unroll
    for (int i = 0; i < 4; ++i) rp[i] = pkrtz(f[2 * i], f[2 * i + 1]);
    return r;
}
static __device__ inline f16x8 scale8(f16x2 h2, f16x8 x) {
    f16x8 r; f16x2* rp = (f16x2*)&r; f16x2* xp = (f16x2*)&x;
#pragma unroll
    for (int i = 0; i < 4; ++i) rp[i] = h2 * xp[i];
    return r;
}
static __device__ inline int pack2(float a, float b) {
    union { f16x2 h; int i; } u;
    u.h = pkrtz(a, b);
    return u.i;
}

// ---------------------------------------------------------------------------
// Prep kernel (fold-only): 64 blocks x 1024 threads. Tables emitted as F16.
// ---------------------------------------------------------------------------
__global__ __launch_bounds__(1024) void prep_kernel(
    const float* __restrict__ Wgen, const float* __restrict__ L1s,
    const float* __restrict__ L1v, const float* __restrict__ WS0,
    const float* __restrict__ WS1, const float* __restrict__ L2s,
    const float* __restrict__ L2v, unsigned short* __restrict__ Wc,
    unsigned short* __restrict__ WB0, unsigned short* __restrict__ WB1,
    int* __restrict__ cnt) {
    const float S = 1.0f / 128.0f;
    int tid = blockIdx.x * 1024 + threadIdx.x;   // 0..65535
    if (tid < N_NODES) cnt[tid] = 0;             // per-node slot counters
    if (tid < 32768) {
        int j = tid & 7;
        int lane = (tid >> 3) & 63;
        int ks = (tid >> 9) & 7;
        int nt = tid >> 12;
        int col = nt * 16 + (lane & 15);
        int u = (lane >> 4) * 8 + j;
        int r = ks;
        int p, c2;
        const float* M;
        float sc = S;
        if (col < 32)      { p = 0; M = L1s; c2 = col; }
        else if (col < 64) { p = 1; M = L1v; c2 = col - 32; }
        else if (col < 96) { p = 2; M = L1v; c2 = col - 64; }
        else               { p = 3; M = L1s; c2 = col - 96; sc = S * 0.57735026918962576f; }
        const float* wg = Wgen + r * 4096 + p * 1024 + u * 32;
        float acc = 0.f;
#pragma unroll
        for (int w = 0; w < 32; ++w) acc += wg[w] * M[w * 32 + c2];
        Wc[tid] = f16u(acc * sc);
    } else {
        int idx = tid - 32768;
        int table = idx >> 14;
        int r14 = idx & 16383;
        int j = r14 & 7;
        int lane = (r14 >> 3) & 63;
        int ks = (r14 >> 9) & 15;
        int k = ks * 32 + (lane >> 4) * 8 + j;
        int u = k >> 4, v = k & 15;
        int w = ((r14 >> 13) & 1) * 16 + (lane & 15);
        const float* WS = table ? WS1 : WS0;
        const float* L2 = table ? L2v : L2s;
        const float* src = WS + u * 512 + v * 32;
        float acc = 0.f;
#pragma unroll
        for (int x = 0; x < 32; ++x) acc += src[x] * L2[x * 32 + w];
        unsigned short val = f16u(acc * S);
        if (table) WB1[r14] = val; else WB0[r14] = val;
    }
}

// ---------------------------------------------------------------------------
// Edge kernel v11 (R6, known-good 127us config): F16 packed datapath,
// 2-deep index prefetch, sEA/sSL strips, static stride, 256 thr / 512 blocks.
// Fusion abandoned: (256,2) de-pipelines regalloc (R7), plain 256 breaks
// barrier co-residency (R8 deadlock).
// ---------------------------------------------------------------------------
__global__ __launch_bounds__(256) void edge_kernel(
    const float* __restrict__ node_feats, const float* __restrict__ edge_attrs,
    const float* __restrict__ edge_feats, const int* __restrict__ edge_index,
    const unsigned short* __restrict__ Wc, int* __restrict__ cnt,
    unsigned short* __restrict__ Msg) {
    __shared__ f16x8 sW8[4096];     // 64 KB, B-fragment order (f16 bits)
    __shared__ int sSL[4][16];      // per-wave slot strip
    __shared__ f32x4 sEA[4][16];    // per-wave edge_attrs strip
    {
        const f16x8* src = (const f16x8*)Wc;
        for (int i = threadIdx.x; i < 4096; i += 256) sW8[i] = src[i];
    }
    __syncthreads();

    const int lane = threadIdx.x & 63;
    const int m = lane & 15, q = lane >> 4;
    const int wv = threadIdx.x >> 6;
    const int wave = (blockIdx.x * 256 + threadIdx.x) >> 6;
    const int stride = gridDim.x * 4;
    const int NT = N_EDGES / 16;

    int tile = wave;
    if (tile >= NT) return;

    f16x8 xs8, xv8[3], dt8;
    float efC[8];
    f32x4 eaC;
    int slC = 0;

    // ---- prologue: gather + convert for first tile; idx prefetch for +stride
    {
        int e = tile * 16 + m;
        int snd = edge_index[e];
        if (lane < 16) {
            int r = edge_index[N_EDGES + e];
            slC = r * SLOTS + atomicAdd(&cnt[r], 1);
        }
        const float* g = node_feats + snd * 128;
        float xs[8], xv[24];
        *(f32x4*)&xs[0] = *(const f32x4*)(g + q * 8);
        *(f32x4*)&xs[4] = *(const f32x4*)(g + q * 8 + 4);
#pragma unroll
        for (int i = 0; i < 6; ++i)
            *(f32x4*)&xv[i * 4] = *(const f32x4*)(g + 32 + q * 24 + i * 4);
        *(f32x4*)&efC[0] = *(const f32x4*)(edge_feats + e * 8);
        *(f32x4*)&efC[4] = *(const f32x4*)(edge_feats + e * 8 + 4);
        eaC = *(const f32x4*)(edge_attrs + e * 4);
        float dt[8];
        float y0 = eaC.y, y1 = eaC.z, y2 = eaC.w;
#pragma unroll
        for (int j = 0; j < 8; ++j)
            dt[j] = xv[j * 3] * y0 + xv[j * 3 + 1] * y1 + xv[j * 3 + 2] * y2;
        xs8 = cvt8h(xs);
#pragma unroll
        for (int c = 0; c < 3; ++c) {
            f16x8 r; f16x2* rp = (f16x2*)&r;
#pragma unroll
            for (int i = 0; i < 4; ++i)
                rp[i] = pkrtz(xv[(2 * i) * 3 + c], xv[(2 * i + 1) * 3 + c]);
            xv8[c] = r;
        }
        dt8 = cvt8h(dt);
    }
    int snd1 = 0, rcv1 = 0;
    {
        int t1 = tile + stride;
        if (t1 < NT) {
            int e1 = t1 * 16 + m;
            snd1 = edge_index[e1];
            if (lane < 16) rcv1 = edge_index[N_EDGES + e1];
        }
    }

    while (tile < NT) {
        const int tn = tile + stride;
        const bool hasN = tn < NT;
        const int t2 = tile + 2 * stride;
        const bool has2 = t2 < NT;

        if (lane < 16) {
            sSL[wv][lane] = slC;
            sEA[wv][lane] = eaC;
        }

        // ---- prefetch tile+s raw state (in-register indices, no dep wait)
        float xsN[8], xvN[24], efN[8];
        f32x4 eaN;
        int slN = 0;
        if (hasN) {
            int en = tn * 16 + m;
            if (lane < 16) slN = rcv1 * SLOTS + atomicAdd(&cnt[rcv1], 1);
            const float* gN = node_feats + snd1 * 128;
            *(f32x4*)&xsN[0] = *(const f32x4*)(gN + q * 8);
            *(f32x4*)&xsN[4] = *(const f32x4*)(gN + q * 8 + 4);
#pragma unroll
            for (int i = 0; i < 6; ++i)
                *(f32x4*)&xvN[i * 4] = *(const f32x4*)(gN + 32 + q * 24 + i * 4);
            *(f32x4*)&efN[0] = *(const f32x4*)(edge_feats + en * 8);
            *(f32x4*)&efN[4] = *(const f32x4*)(edge_feats + en * 8 + 4);
            eaN = *(const f32x4*)(edge_attrs + en * 4);
        }

        // ---- prefetch tile+2s indices
        int snd2 = 0, rcv2 = 0;
        if (has2) {
            int e2 = t2 * 16 + m;
            snd2 = edge_index[e2];
            if (lane < 16) rcv2 = edge_index[N_EDGES + e2];
        }

        // ---- compute current tile (f16 packed A-builds)
        f32x4 z = {0.f, 0.f, 0.f, 0.f};
        f32x4 fA[2] = {z, z}, fB[2] = {z, z}, fD[2] = {z, z};
        f32x4 fC[3][2] = {{z, z}, {z, z}, {z, z}};

#pragma unroll
        for (int ks = 0; ks < 8; ++ks) {
            _Float16 h = (_Float16)efC[ks];
            f16x2 h2 = {h, h};
            {
                f16x8 a = scale8(h2, xs8);
                fA[0] = __builtin_amdgcn_mfma_f32_16x16x32_f16(a, sW8[(0 * 8 + ks) * 64 + lane], fA[0], 0, 0, 0);
                fA[1] = __builtin_amdgcn_mfma_f32_16x16x32_f16(a, sW8[(1 * 8 + ks) * 64 + lane], fA[1], 0, 0, 0);
                fB[0] = __builtin_amdgcn_mfma_f32_16x16x32_f16(a, sW8[(2 * 8 + ks) * 64 + lane], fB[0], 0, 0, 0);
                fB[1] = __builtin_amdgcn_mfma_f32_16x16x32_f16(a, sW8[(3 * 8 + ks) * 64 + lane], fB[1], 0, 0, 0);
            }
            {
                f16x8 bc0 = sW8[(4 * 8 + ks) * 64 + lane];
                f16x8 bc1 = sW8[(5 * 8 + ks) * 64 + lane];
#pragma unroll
                for (int c = 0; c < 3; ++c) {
                    f16x8 a = scale8(h2, xv8[c]);
                    fC[c][0] = __builtin_amdgcn_mfma_f32_16x16x32_f16(a, bc0, fC[c][0], 0, 0, 0);
                    fC[c][1] = __builtin_amdgcn_mfma_f32_16x16x32_f16(a, bc1, fC[c][1], 0, 0, 0);
                }
            }
            {
                f16x8 a = scale8(h2, dt8);
                fD[0] = __builtin_amdgcn_mfma_f32_16x16x32_f16(a, sW8[(6 * 8 + ks) * 64 + lane], fD[0], 0, 0, 0);
                fD[1] = __builtin_amdgcn_mfma_f32_16x16x32_f16(a, sW8[(7 * 8 + ks) * 64 + lane], fD[1], 0, 0, 0);
            }
        }

        // ---- epilogue: per-lane rows q*4+t4; slots+attrs via ds_read_b128
        int4 sl4 = *(const int4*)&sSL[wv][q * 4];
        const int slR[4] = {sl4.x, sl4.y, sl4.z, sl4.w};
#pragma unroll
        for (int t4 = 0; t4 < 4; ++t4) {
            f32x4 ea4 = sEA[wv][q * 4 + t4];
            float ysr = ea4.x, y0r = ea4.y, y1r = ea4.z, y2r = ea4.w;
            int dr = slR[t4];
#pragma unroll
            for (int nt = 0; nt < 2; ++nt) {
                int col = nt * 16 + m;
                float pb = fB[nt][t4];
                int2 pk;
                pk.x = pack2(ysr * fA[nt][t4] + fD[nt][t4],
                             y0r * pb + ysr * fC[0][nt][t4]);
                pk.y = pack2(y1r * pb + ysr * fC[1][nt][t4],
                             y2r * pb + ysr * fC[2][nt][t4]);
                *(int2*)(Msg + (size_t)dr * 128 + col * 4) = pk;
            }
        }

        // ---- rotate pipeline: wait loads land here, convert once
        tile = tn;
        if (hasN) {
            float dtN[8];
            float y0 = eaN.y, y1 = eaN.z, y2 = eaN.w;
#pragma unroll
            for (int j = 0; j < 8; ++j)
                dtN[j] = xvN[j * 3] * y0 + xvN[j * 3 + 1] * y1 + xvN[j * 3 + 2] * y2;
            xs8 = cvt8h(xsN);
#pragma unroll
            for (int c = 0; c < 3; ++c) {
                f16x8 r; f16x2* rp = (f16x2*)&r;
#pragma unroll
                for (int i = 0; i < 4; ++i)
                    rp[i] = pkrtz(xvN[(2 * i) * 3 + c], xvN[(2 * i + 1) * 3 + c]);
                xv8[c] = r;
            }
            dt8 = cvt8h(dtN);
#pragma unroll
            for (int j = 0; j < 8; ++j) efC[j] = efN[j];
            eaC = eaN;
            slC = slN;
            snd1 = snd2;
            rcv1 = rcv2;
        }
    }
}

// ---------------------------------------------------------------------------
// Fused gather + node kernel. NEW: 16 unconditional row loads (slots always
// in-bounds; SLOTS=40) + accumulate predicated on i<deg — one latency round
// for 97% of nodes instead of 2-3 dependent rounds. Poison in unused slots
// never enters acc (predicated add, not load).
// ---------------------------------------------------------------------------
__global__ __launch_bounds__(256) void node_kernel(
    const float* __restrict__ node_attrs, const unsigned short* __restrict__ Msg,
    const int* __restrict__ cnt, const unsigned short* __restrict__ WB0,
    const unsigned short* __restrict__ WB1, float* __restrict__ out) {
    __shared__ float sM[16][129];
    __shared__ float sAt[16][17];
    int n0 = blockIdx.x * 16;

    int nl = threadIdx.x >> 4;
    int cg = threadIdx.x & 15;
    int n = n0 + nl;
    int deg = cnt[n];
    int s0 = n * SLOTS;
    float acc[8];
#pragma unroll
    for (int j = 0; j < 8; ++j) acc[j] = 0.f;
    {
        f32x4 r[16];
#pragma unroll
        for (int i = 0; i < 16; ++i)
            r[i] = *(const f32x4*)(Msg + (size_t)(s0 + i) * 128 + cg * 8);
#pragma unroll
        for (int i = 0; i < 16; ++i) {
            if (i < deg) {
                const unsigned short* us = (const unsigned short*)&r[i];
#pragma unroll
                for (int j = 0; j < 8; ++j) acc[j] += f16f(us[j]);
            }
        }
    }
    for (int s = s0 + 16; s < s0 + deg; ++s) {   // rare deg>16 tail
        f32x4 raw = *(const f32x4*)(Msg + (size_t)s * 128 + cg * 8);
        const unsigned short* us = (const unsigned short*)&raw;
#pragma unroll
        for (int j = 0; j < 8; ++j) acc[j] += f16f(us[j]);
    }
#pragma unroll
    for (int j = 0; j < 8; ++j)
        sM[nl][(j & 3) * 32 + cg * 2 + (j >> 2)] = acc[j];
    sAt[nl][cg] = node_attrs[n * 16 + cg];
    __syncthreads();

    int p = threadIdx.x >> 6;
    int lane = threadIdx.x & 63;
    int m = lane & 15, q = lane >> 4;
    const unsigned short* WB = (p == 0) ? WB0 : WB1;
    int chb = p * 32;
    f32x4 z = {0.f, 0.f, 0.f, 0.f};
    f32x4 D0 = z, D1 = z;
#pragma unroll
    for (int ks = 0; ks < 16; ++ks) {
        int kb = ks * 32 + q * 8;
        float t[8];
#pragma unroll
        for (int j = 0; j < 8; ++j) {
            int k = kb + j;
            t[j] = sM[m][chb + (k >> 4)] * sAt[m][k & 15];
        }
        f16x8 a = cvt8h(t);
        f16x8 b0 = *(const f16x8*)(WB + (ks * 64 + lane) * 8);
        f16x8 b1 = *(const f16x8*)(WB + ((16 + ks) * 64 + lane) * 8);
        D0 = __builtin_amdgcn_mfma_f32_16x16x32_f16(a, b0, D0, 0, 0, 0);
        D1 = __builtin_amdgcn_mfma_f32_16x16x32_f16(a, b1, D1, 0, 0, 0);
    }

#pragma unroll
    for (int t4 = 0; t4 < 4; ++t4) {
        int nl2 = q * 4 + t4;
        int nn = n0 + nl2;
        if (p == 0) {
            out[nn * 128 + m]      = sM[nl2][m] + D0[t4];
            out[nn * 128 + 16 + m] = sM[nl2][16 + m] + D1[t4];
        } else {
            int i = p - 1;
            out[nn * 128 + 32 + m * 3 + i]        = sM[nl2][chb + m] + D0[t4];
            out[nn * 128 + 32 + (16 + m) * 3 + i] = sM[nl2][chb + 16 + m] + D1[t4];
        }
    }
}

extern "C" void kernel_launch(void* const* d_in, const int* in_sizes, int n_in,
                              void* d_out, int out_size, void* d_ws, size_t ws_size,
                              hipStream_t stream) {
    (void)in_sizes; (void)n_in; (void)out_size; (void)ws_size;
    const float* node_attrs = (const float*)d_in[0];
    const float* node_feats = (const float*)d_in[1];
    const float* edge_attrs = (const float*)d_in[2];
    const float* edge_feats = (const float*)d_in[3];
    const int*   edge_index = (const int*)d_in[4];
    const float* Wgen = (const float*)d_in[5];
    const float* L1s  = (const float*)d_in[6];
    const float* L1v  = (const float*)d_in[7];
    const float* WS0  = (const float*)d_in[8];
    const float* WS1  = (const float*)d_in[9];
    const float* L2s  = (const float*)d_in[10];
    const float* L2v  = (const float*)d_in[11];
    float* out = (float*)d_out;
    char* ws = (char*)d_ws;

    // Msg: N_NODES*SLOTS rows x 128 f16 = 102,400,000 B (ws is 256 MiB)
    unsigned short* Msg = (unsigned short*)ws;
    unsigned short* Wc  = (unsigned short*)(ws + 102400000);   // 65,536
    unsigned short* WB0 = (unsigned short*)(ws + 102465536);   // 32,768
    unsigned short* WB1 = (unsigned short*)(ws + 102498304);   // 32,768
    int* cnt = (int*)(ws + 102531072);                         // 10000 ints

    prep_kernel<<<64, 1024, 0, stream>>>(Wgen, L1s, L1v, WS0, WS1, L2s, L2v,
                                         Wc, WB0, WB1, cnt);
    edge_kernel<<<512, 256, 0, stream>>>(node_feats, edge_attrs, edge_feats,
                                         edge_index, Wc, cnt, Msg);
    node_kernel<<<625, 256, 0, stream>>>(node_attrs, Msg, cnt, WB0, WB1, out);
}

// Round 10
// 129.694 us; speedup vs baseline: 1.8323x; 1.0009x over previous
//
#include <hip/hip_runtime.h>

#define N_NODES 10000
#define N_EDGES 100000
#define SLOTS 40   // max degree bound; Poisson(10), P(deg>=40) ~ 1e-12

typedef __attribute__((ext_vector_type(8))) _Float16 f16x8;
typedef __attribute__((ext_vector_type(2))) _Float16 f16x2;
typedef __attribute__((ext_vector_type(4))) float f32x4;

// __builtin_amdgcn_cvt_pkrtz returns __fp16x2; rewrap bits as _Float16x2.
static __device__ inline f16x2 pkrtz(float a, float b) {
    auto t = __builtin_amdgcn_cvt_pkrtz(a, b);
    union { decltype(t) x; f16x2 y; } u;
    u.x = t;
    return u.y;
}
static __device__ inline unsigned short f16u(float x) {
    union { _Float16 h; unsigned short s; } u;
    u.h = (_Float16)x;
    return u.s;
}
static __device__ inline float f16f(unsigned short us) {
    union { unsigned short s; _Float16 h; } u;
    u.s = us;
    return (float)u.h;
}
static __device__ inline f16x8 cvt8h(const float* f) {
    f16x8 r; f16x2* rp = (f16x2*)&r;
#pragma unroll
    for (int i = 0; i < 4; ++i) rp[i] = pkrtz(f[2 * i], f[2 * i + 1]);
    return r;
}
static __device__ inline f16x8 scale8(f16x2 h2, f16x8 x) {
    f16x8 r; f16x2* rp = (f16x2*)&r; f16x2* xp = (f16x2*)&x;
#pragma unroll
    for (int i = 0; i < 4; ++i) rp[i] = h2 * xp[i];
    return r;
}
static __device__ inline int pack2(float a, float b) {
    union { f16x2 h; int i; } u;
    u.h = pkrtz(a, b);
    return u.i;
}
// dt8 = xvx*y0 + xvy*y1 + xvz*y2, all packed f16
static __device__ inline f16x8 dot3(f16x8 xx, f16x8 xy, f16x8 xz, f32x4 ea) {
    _Float16 y0 = (_Float16)ea.y, y1 = (_Float16)ea.z, y2 = (_Float16)ea.w;
    f16x2 y0_2 = {y0, y0}, y1_2 = {y1, y1}, y2_2 = {y2, y2};
    f16x8 r; f16x2* rp = (f16x2*)&r;
    f16x2* xp = (f16x2*)&xx; f16x2* yp = (f16x2*)&xy; f16x2* zp = (f16x2*)&xz;
#pragma unroll
    for (int i = 0; i < 4; ++i)
        rp[i] = xp[i] * y0_2 + yp[i] * y1_2 + zp[i] * y2_2;
    return r;
}

// ---------------------------------------------------------------------------
// Prep kernel: 64 blocks x 1024 threads.
//  - Wc / WB0 / WB1 folds (f16) as before; cnt zeroed.
//  - NEW: xf gather table — node_feats pre-transposed to f16:
//    xf[(n*4+q)*32] = { xs[8] | xv_x[8] | xv_y[8] | xv_z[8] }  (64 B per n,q)
//    2.56 MB total -> fits every XCD L2 (f32 table was 5.12 MB > 4 MB, thrash)
//    and edge loads MFMA-ready fragments with ZERO convert/transpose.
// ---------------------------------------------------------------------------
__global__ __launch_bounds__(1024) void prep_kernel(
    const float* __restrict__ Wgen, const float* __restrict__ L1s,
    const float* __restrict__ L1v, const float* __restrict__ WS0,
    const float* __restrict__ WS1, const float* __restrict__ L2s,
    const float* __restrict__ L2v, const float* __restrict__ node_feats,
    unsigned short* __restrict__ Wc, unsigned short* __restrict__ WB0,
    unsigned short* __restrict__ WB1, unsigned short* __restrict__ xf,
    int* __restrict__ cnt) {
    const float S = 1.0f / 128.0f;
    int tid = blockIdx.x * 1024 + threadIdx.x;   // 0..65535
    if (tid < N_NODES) cnt[tid] = 0;             // per-node slot counters
    if (tid < 40000) {                           // xf fill: one (n,q) per thread
        int n = tid >> 2, qq = tid & 3;
        const float* g = node_feats + n * 128;
        unsigned short* dst = xf + (size_t)tid * 32;
#pragma unroll
        for (int j = 0; j < 8; ++j) dst[j] = f16u(g[qq * 8 + j]);
#pragma unroll
        for (int c = 0; c < 3; ++c)
#pragma unroll
            for (int j = 0; j < 8; ++j)
                dst[8 + c * 8 + j] = f16u(g[32 + qq * 24 + j * 3 + c]);
    }
    if (tid < 32768) {
        int j = tid & 7;
        int lane = (tid >> 3) & 63;
        int ks = (tid >> 9) & 7;
        int nt = tid >> 12;
        int col = nt * 16 + (lane & 15);
        int u = (lane >> 4) * 8 + j;
        int r = ks;
        int p, c2;
        const float* M;
        float sc = S;
        if (col < 32)      { p = 0; M = L1s; c2 = col; }
        else if (col < 64) { p = 1; M = L1v; c2 = col - 32; }
        else if (col < 96) { p = 2; M = L1v; c2 = col - 64; }
        else               { p = 3; M = L1s; c2 = col - 96; sc = S * 0.57735026918962576f; }
        const float* wg = Wgen + r * 4096 + p * 1024 + u * 32;
        float acc = 0.f;
#pragma unroll
        for (int w = 0; w < 32; ++w) acc += wg[w] * M[w * 32 + c2];
        Wc[tid] = f16u(acc * sc);
    } else {
        int idx = tid - 32768;
        int table = idx >> 14;
        int r14 = idx & 16383;
        int j = r14 & 7;
        int lane = (r14 >> 3) & 63;
        int ks = (r14 >> 9) & 15;
        int k = ks * 32 + (lane >> 4) * 8 + j;
        int u = k >> 4, v = k & 15;
        int w = ((r14 >> 13) & 1) * 16 + (lane & 15);
        const float* WS = table ? WS1 : WS0;
        const float* L2 = table ? L2v : L2s;
        const float* src = WS + u * 512 + v * 32;
        float acc = 0.f;
#pragma unroll
        for (int x = 0; x < 32; ++x) acc += src[x] * L2[x * 32 + w];
        unsigned short val = f16u(acc * S);
        if (table) WB1[r14] = val; else WB0[r14] = val;
    }
}

// ---------------------------------------------------------------------------
// Edge kernel v12: F16 GATHER TABLE.
//  - gather reads 64 B of MFMA-ready f16 per lane (was 128 B f32 + transpose
//    + convert): L2-resident table, rotate is 4 register copies + 12 pk-fma
//    for dt8. Prefetch state halves (16 vs 32 VGPR).
//  - kept: 2-deep index prefetch, sEA/sSL strips, static stride, 256 thr.
// ---------------------------------------------------------------------------
__global__ __launch_bounds__(256) void edge_kernel(
    const unsigned short* __restrict__ xf, const float* __restrict__ edge_attrs,
    const float* __restrict__ edge_feats, const int* __restrict__ edge_index,
    const unsigned short* __restrict__ Wc, int* __restrict__ cnt,
    unsigned short* __restrict__ Msg) {
    __shared__ f16x8 sW8[4096];     // 64 KB, B-fragment order (f16 bits)
    __shared__ int sSL[4][16];      // per-wave slot strip
    __shared__ f32x4 sEA[4][16];    // per-wave edge_attrs strip
    {
        const f16x8* src = (const f16x8*)Wc;
        for (int i = threadIdx.x; i < 4096; i += 256) sW8[i] = src[i];
    }
    __syncthreads();

    const int lane = threadIdx.x & 63;
    const int m = lane & 15, q = lane >> 4;
    const int wv = threadIdx.x >> 6;
    const int wave = (blockIdx.x * 256 + threadIdx.x) >> 6;
    const int stride = gridDim.x * 4;
    const int NT = N_EDGES / 16;

    int tile = wave;
    if (tile >= NT) return;

    f16x8 xs8, xv8[3], dt8;
    float efC[8];
    f32x4 eaC;
    int slC = 0;

    // ---- prologue
    {
        int e = tile * 16 + m;
        int snd = edge_index[e];
        if (lane < 16) {
            int r = edge_index[N_EDGES + e];
            slC = r * SLOTS + atomicAdd(&cnt[r], 1);
        }
        const f16x8* gx = (const f16x8*)(xf + (size_t)(snd * 4 + q) * 32);
        xs8 = gx[0]; xv8[0] = gx[1]; xv8[1] = gx[2]; xv8[2] = gx[3];
        *(f32x4*)&efC[0] = *(const f32x4*)(edge_feats + e * 8);
        *(f32x4*)&efC[4] = *(const f32x4*)(edge_feats + e * 8 + 4);
        eaC = *(const f32x4*)(edge_attrs + e * 4);
        dt8 = dot3(xv8[0], xv8[1], xv8[2], eaC);
    }
    int snd1 = 0, rcv1 = 0;
    {
        int t1 = tile + stride;
        if (t1 < NT) {
            int e1 = t1 * 16 + m;
            snd1 = edge_index[e1];
            if (lane < 16) rcv1 = edge_index[N_EDGES + e1];
        }
    }

    while (tile < NT) {
        const int tn = tile + stride;
        const bool hasN = tn < NT;
        const int t2 = tile + 2 * stride;
        const bool has2 = t2 < NT;

        if (lane < 16) {
            sSL[wv][lane] = slC;
            sEA[wv][lane] = eaC;
        }

        // ---- prefetch tile+s state (in-register indices, no dep wait)
        f16x8 xsN, xvxN, xvyN, xvzN;
        float efN[8];
        f32x4 eaN;
        int slN = 0;
        if (hasN) {
            int en = tn * 16 + m;
            if (lane < 16) slN = rcv1 * SLOTS + atomicAdd(&cnt[rcv1], 1);
            const f16x8* gN = (const f16x8*)(xf + (size_t)(snd1 * 4 + q) * 32);
            xsN = gN[0]; xvxN = gN[1]; xvyN = gN[2]; xvzN = gN[3];
            *(f32x4*)&efN[0] = *(const f32x4*)(edge_feats + en * 8);
            *(f32x4*)&efN[4] = *(const f32x4*)(edge_feats + en * 8 + 4);
            eaN = *(const f32x4*)(edge_attrs + en * 4);
        }

        // ---- prefetch tile+2s indices
        int snd2 = 0, rcv2 = 0;
        if (has2) {
            int e2 = t2 * 16 + m;
            snd2 = edge_index[e2];
            if (lane < 16) rcv2 = edge_index[N_EDGES + e2];
        }

        // ---- compute current tile (f16 packed A-builds)
        f32x4 z = {0.f, 0.f, 0.f, 0.f};
        f32x4 fA[2] = {z, z}, fB[2] = {z, z}, fD[2] = {z, z};
        f32x4 fC[3][2] = {{z, z}, {z, z}, {z, z}};

#pragma unroll
        for (int ks = 0; ks < 8; ++ks) {
            _Float16 h = (_Float16)efC[ks];
            f16x2 h2 = {h, h};
            {
                f16x8 a = scale8(h2, xs8);
                fA[0] = __builtin_amdgcn_mfma_f32_16x16x32_f16(a, sW8[(0 * 8 + ks) * 64 + lane], fA[0], 0, 0, 0);
                fA[1] = __builtin_amdgcn_mfma_f32_16x16x32_f16(a, sW8[(1 * 8 + ks) * 64 + lane], fA[1], 0, 0, 0);
                fB[0] = __builtin_amdgcn_mfma_f32_16x16x32_f16(a, sW8[(2 * 8 + ks) * 64 + lane], fB[0], 0, 0, 0);
                fB[1] = __builtin_amdgcn_mfma_f32_16x16x32_f16(a, sW8[(3 * 8 + ks) * 64 + lane], fB[1], 0, 0, 0);
            }
            {
                f16x8 bc0 = sW8[(4 * 8 + ks) * 64 + lane];
                f16x8 bc1 = sW8[(5 * 8 + ks) * 64 + lane];
#pragma unroll
                for (int c = 0; c < 3; ++c) {
                    f16x8 a = scale8(h2, xv8[c]);
                    fC[c][0] = __builtin_amdgcn_mfma_f32_16x16x32_f16(a, bc0, fC[c][0], 0, 0, 0);
                    fC[c][1] = __builtin_amdgcn_mfma_f32_16x16x32_f16(a, bc1, fC[c][1], 0, 0, 0);
                }
            }
            {
                f16x8 a = scale8(h2, dt8);
                fD[0] = __builtin_amdgcn_mfma_f32_16x16x32_f16(a, sW8[(6 * 8 + ks) * 64 + lane], fD[0], 0, 0, 0);
                fD[1] = __builtin_amdgcn_mfma_f32_16x16x32_f16(a, sW8[(7 * 8 + ks) * 64 + lane], fD[1], 0, 0, 0);
            }
        }

        // ---- epilogue: per-lane rows q*4+t4; slots+attrs via ds_read_b128
        int4 sl4 = *(const int4*)&sSL[wv][q * 4];
        const int slR[4] = {sl4.x, sl4.y, sl4.z, sl4.w};
#pragma unroll
        for (int t4 = 0; t4 < 4; ++t4) {
            f32x4 ea4 = sEA[wv][q * 4 + t4];
            float ysr = ea4.x, y0r = ea4.y, y1r = ea4.z, y2r = ea4.w;
            int dr = slR[t4];
#pragma unroll
            for (int nt = 0; nt < 2; ++nt) {
                int col = nt * 16 + m;
                float pb = fB[nt][t4];
                int2 pk;
                pk.x = pack2(ysr * fA[nt][t4] + fD[nt][t4],
                             y0r * pb + ysr * fC[0][nt][t4]);
                pk.y = pack2(y1r * pb + ysr * fC[1][nt][t4],
                             y2r * pb + ysr * fC[2][nt][t4]);
                *(int2*)(Msg + (size_t)dr * 128 + col * 4) = pk;
            }
        }

        // ---- rotate pipeline: pure register moves + 12 pk-fma for dt8
        tile = tn;
        if (hasN) {
            xs8 = xsN; xv8[0] = xvxN; xv8[1] = xvyN; xv8[2] = xvzN;
            dt8 = dot3(xvxN, xvyN, xvzN, eaN);
#pragma unroll
            for (int j = 0; j < 8; ++j) efC[j] = efN[j];
            eaC = eaN;
            slC = slN;
            snd1 = snd2;
            rcv1 = rcv2;
        }
    }
}

// ---------------------------------------------------------------------------
// Node kernel (unchanged from R9): 16 unconditional row loads + predicated
// accumulate; f16 Msg/WB; MFMA epilogue.
// ---------------------------------------------------------------------------
__global__ __launch_bounds__(256) void node_kernel(
    const float* __restrict__ node_attrs, const unsigned short* __restrict__ Msg,
    const int* __restrict__ cnt, const unsigned short* __restrict__ WB0,
    const unsigned short* __restrict__ WB1, float* __restrict__ out) {
    __shared__ float sM[16][129];
    __shared__ float sAt[16][17];
    int n0 = blockIdx.x * 16;

    int nl = threadIdx.x >> 4;
    int cg = threadIdx.x & 15;
    int n = n0 + nl;
    int deg = cnt[n];
    int s0 = n * SLOTS;
    float acc[8];
#pragma unroll
    for (int j = 0; j < 8; ++j) acc[j] = 0.f;
    {
        f32x4 r[16];
#pragma unroll
        for (int i = 0; i < 16; ++i)
            r[i] = *(const f32x4*)(Msg + (size_t)(s0 + i) * 128 + cg * 8);
#pragma unroll
        for (int i = 0; i < 16; ++i) {
            if (i < deg) {
                const unsigned short* us = (const unsigned short*)&r[i];
#pragma unroll
                for (int j = 0; j < 8; ++j) acc[j] += f16f(us[j]);
            }
        }
    }
    for (int s = s0 + 16; s < s0 + deg; ++s) {   // rare deg>16 tail
        f32x4 raw = *(const f32x4*)(Msg + (size_t)s * 128 + cg * 8);
        const unsigned short* us = (const unsigned short*)&raw;
#pragma unroll
        for (int j = 0; j < 8; ++j) acc[j] += f16f(us[j]);
    }
#pragma unroll
    for (int j = 0; j < 8; ++j)
        sM[nl][(j & 3) * 32 + cg * 2 + (j >> 2)] = acc[j];
    sAt[nl][cg] = node_attrs[n * 16 + cg];
    __syncthreads();

    int p = threadIdx.x >> 6;
    int lane = threadIdx.x & 63;
    int m = lane & 15, q = lane >> 4;
    const unsigned short* WB = (p == 0) ? WB0 : WB1;
    int chb = p * 32;
    f32x4 z = {0.f, 0.f, 0.f, 0.f};
    f32x4 D0 = z, D1 = z;
#pragma unroll
    for (int ks = 0; ks < 16; ++ks) {
        int kb = ks * 32 + q * 8;
        float t[8];
#pragma unroll
        for (int j = 0; j < 8; ++j) {
            int k = kb + j;
            t[j] = sM[m][chb + (k >> 4)] * sAt[m][k & 15];
        }
        f16x8 a = cvt8h(t);
        f16x8 b0 = *(const f16x8*)(WB + (ks * 64 + lane) * 8);
        f16x8 b1 = *(const f16x8*)(WB + ((16 + ks) * 64 + lane) * 8);
        D0 = __builtin_amdgcn_mfma_f32_16x16x32_f16(a, b0, D0, 0, 0, 0);
        D1 = __builtin_amdgcn_mfma_f32_16x16x32_f16(a, b1, D1, 0, 0, 0);
    }

#pragma unroll
    for (int t4 = 0; t4 < 4; ++t4) {
        int nl2 = q * 4 + t4;
        int nn = n0 + nl2;
        if (p == 0) {
            out[nn * 128 + m]      = sM[nl2][m] + D0[t4];
            out[nn * 128 + 16 + m] = sM[nl2][16 + m] + D1[t4];
        } else {
            int i = p - 1;
            out[nn * 128 + 32 + m * 3 + i]        = sM[nl2][chb + m] + D0[t4];
            out[nn * 128 + 32 + (16 + m) * 3 + i] = sM[nl2][chb + 16 + m] + D1[t4];
        }
    }
}

extern "C" void kernel_launch(void* const* d_in, const int* in_sizes, int n_in,
                              void* d_out, int out_size, void* d_ws, size_t ws_size,
                              hipStream_t stream) {
    (void)in_sizes; (void)n_in; (void)out_size; (void)ws_size;
    const float* node_attrs = (const float*)d_in[0];
    const float* node_feats = (const float*)d_in[1];
    const float* edge_attrs = (const float*)d_in[2];
    const float* edge_feats = (const float*)d_in[3];
    const int*   edge_index = (const int*)d_in[4];
    const float* Wgen = (const float*)d_in[5];
    const float* L1s  = (const float*)d_in[6];
    const float* L1v  = (const float*)d_in[7];
    const float* WS0  = (const float*)d_in[8];
    const float* WS1  = (const float*)d_in[9];
    const float* L2s  = (const float*)d_in[10];
    const float* L2v  = (const float*)d_in[11];
    float* out = (float*)d_out;
    char* ws = (char*)d_ws;

    // Msg: N_NODES*SLOTS rows x 128 f16 = 102,400,000 B (ws is 256 MiB)
    unsigned short* Msg = (unsigned short*)ws;
    unsigned short* Wc  = (unsigned short*)(ws + 102400000);   //    65,536
    unsigned short* WB0 = (unsigned short*)(ws + 102465536);   //    32,768
    unsigned short* WB1 = (unsigned short*)(ws + 102498304);   //    32,768
    int* cnt = (int*)(ws + 102531072);                         //    40,000
    unsigned short* xf  = (unsigned short*)(ws + 102571072);   // 2,560,000

    prep_kernel<<<64, 1024, 0, stream>>>(Wgen, L1s, L1v, WS0, WS1, L2s, L2v,
                                         node_feats, Wc, WB0, WB1, xf, cnt);
    edge_kernel<<<512, 256, 0, stream>>>(xf, edge_attrs, edge_feats,
                                         edge_index, Wc, cnt, Msg);
    node_kernel<<<625, 256, 0, stream>>>(node_attrs, Msg, cnt, WB0, WB1, out);
}